// Round 7
// baseline (183.404 us; speedup 1.0000x reference)
//
#include <hip/hip_runtime.h>
#include <math.h>

// Problem constants (fixed by reference setup_inputs)
constexpr int B = 2, C = 16, H = 160, W = 192, S = 3, D = 48;
constexpr int HW = H * W;          // 30720 = 120 * 256
constexpr int SB = S * B;
constexpr int ND = 2;              // depths per thread (pairing)
constexpr int G = D / ND;          // 24 depth groups

// ------------------------------------------------------------------
// Setup kernel: per (s,b) fold projection chain into
//   A = Ks * R * inv(Kref) (3x3 f64), q = Ks * t (f64)
// so main kernel does p = depth*(A*[u,v,1]) + q.
// ws layout: (s*B+b)*12 doubles = [A row-major 0..8][q 9..11]
// ------------------------------------------------------------------
__global__ void precompute_mats(const float* __restrict__ ref_intr,
                                const float* __restrict__ src_intr,
                                const float* __restrict__ ref_to_src,
                                double* __restrict__ ws)
{
    const int i = threadIdx.x;
    if (i >= SB) return;
    const int b = i % B;

    const float* Kp = ref_intr + b * 9;
    const double a00 = Kp[0], a01 = Kp[1], a02 = Kp[2];
    const double a10 = Kp[3], a11 = Kp[4], a12 = Kp[5];
    const double a20 = Kp[6], a21 = Kp[7], a22 = Kp[8];
    const double c00 =  (a11 * a22 - a12 * a21);
    const double c01 = -(a10 * a22 - a12 * a20);
    const double c02 =  (a10 * a21 - a11 * a20);
    const double c10 = -(a01 * a22 - a02 * a21);
    const double c11 =  (a00 * a22 - a02 * a20);
    const double c12 = -(a00 * a21 - a01 * a20);
    const double c20 =  (a01 * a12 - a02 * a11);
    const double c21 = -(a00 * a12 - a02 * a10);
    const double c22 =  (a00 * a11 - a01 * a10);
    const double invdet = 1.0 / (a00 * c00 + a01 * c01 + a02 * c02);
    const double iK[9] = { c00 * invdet, c10 * invdet, c20 * invdet,
                           c01 * invdet, c11 * invdet, c21 * invdet,
                           c02 * invdet, c12 * invdet, c22 * invdet };

    const float* Tp = ref_to_src + i * 16;
    const float* Ks = src_intr + i * 9;

    double M[9];  // R * inv(K)
    #pragma unroll
    for (int r = 0; r < 3; ++r)
        #pragma unroll
        for (int c = 0; c < 3; ++c)
            M[r * 3 + c] = (double)Tp[r * 4 + 0] * iK[0 + c]
                         + (double)Tp[r * 4 + 1] * iK[3 + c]
                         + (double)Tp[r * 4 + 2] * iK[6 + c];

    double* o = ws + i * 12;
    #pragma unroll
    for (int r = 0; r < 3; ++r) {
        #pragma unroll
        for (int c = 0; c < 3; ++c)
            o[r * 3 + c] = (double)Ks[r * 3 + 0] * M[0 + c]
                         + (double)Ks[r * 3 + 1] * M[3 + c]
                         + (double)Ks[r * 3 + 2] * M[6 + c];
        o[9 + r] = (double)Ks[r * 3 + 0] * (double)Tp[3]
                 + (double)Ks[r * 3 + 1] * (double)Tp[7]
                 + (double)Ks[r * 3 + 2] * (double)Tp[11];
    }
}

// ------------------------------------------------------------------
// Main kernel. 2D grid (Round-4 win): blockIdx.y = b*G+dg keeps b/dg/s
// provably wave-uniform -> depth/mats/channel-bases scalarize (saddr
// loads, SALU address arith). NCHW stride-1 coalesced loads (Round-3
// lesson: NHWC per-thread 64B gathers amplify L1 transactions ~4x).
//
// Register policy (Rounds 2 & 5, HARD RULE): NO min-waves
// __launch_bounds__ — forced caps cause catastrophic scratch spills
// (WRITE_SIZE 11.5MB -> ~1GB). Pressure is managed algorithmically:
//  * fused single-pass NCC (validated Round 5/6, absmax 0.0039):
//    shifted variance sq2 = Σt² - (Σt)²/C, t = f2c - f2[0] — exact
//    identity, cancellation-safe (offset removed BEFORE squaring),
//    no f2[16] array; dot = Σ f1c·f2c directly (Σf1 = 0).
//  * fractions/weights f32 after f64 projection; 1-Newton rcp_f64.
//
// Round-7: ND=2 depth-pairing (93% VALUBusy -> only lever is fewer
// instructions). Pixel-invariant work (ref load/normalize, u/v, per-
// source rays = 18 f64 FMA) now shared across 2 outputs. Source-outer
// / depth-inner keeps ONE ray live (Round-1's 176-VGPR mistake was
// all-3 rays + two 16-reg arrays). Named cost0/cost1 (rule #20).
// Numerics per output identical to Round 6.
// ------------------------------------------------------------------
__global__ __launch_bounds__(256) void plane_sweep_kernel(
    const float* __restrict__ ref_feats,   // [B,C,H,W]
    const float* __restrict__ src_feats,   // [S,B,C,H,W]
    const float* __restrict__ depths,      // [D]
    const double* __restrict__ mats,       // [SB][12]
    float* __restrict__ out)               // [B,D,H,W]
{
    const int pix = blockIdx.x * 256 + threadIdx.x;   // HW = 120*256 exact
    const int by  = blockIdx.y;                       // b*G + dg (scalar)
    const int dg  = by % G;                           // scalar
    const int b   = by / G;                           // scalar

    const int w = pix % W;
    const int h = pix / W;

    // ---- ref fragment: load, zero-mean, norm (f32, well-conditioned) ----
    const float* rb = ref_feats + (size_t)b * C * HW;
    float f1[C];
    float sum1 = 0.0f;
    #pragma unroll
    for (int c = 0; c < C; ++c) { f1[c] = rb[c * HW + pix]; sum1 += f1[c]; }
    const float m1 = sum1 * (1.0f / C);
    float sq1 = 0.0f;
    #pragma unroll
    for (int c = 0; c < C; ++c) { f1[c] -= m1; sq1 = fmaf(f1[c], f1[c], sq1); }
    const float n1 = sqrtf(sq1);

    const double u = (double)w, v = (double)h;
    const double dep0 = (double)depths[dg * ND + 0];   // scalar loads
    const double dep1 = (double)depths[dg * ND + 1];

    float cost0 = 0.0f, cost1 = 0.0f;   // named accumulators (rule #20)

    #pragma unroll 1   // one source's f64 ray live at a time; s uniform
    for (int s = 0; s < S; ++s) {
        const double* Aq = mats + (s * B + b) * 12;   // scalar loads
        const double rx = fma(u, Aq[0], fma(v, Aq[1], Aq[2]));
        const double ry = fma(u, Aq[3], fma(v, Aq[4], Aq[5]));
        const double rz = fma(u, Aq[6], fma(v, Aq[7], Aq[8]));
        const double q0 = Aq[9], q1 = Aq[10], q2 = Aq[11];

        // sb wave-uniform -> saddr loads sharing voffsets
        const float* sb = src_feats + (size_t)(s * B + b) * C * HW;

        auto sample = [&](double depth, float& cost) {
            const double p0 = fma(depth, rx, q0);
            const double p1 = fma(depth, ry, q1);
            const double p2 = fma(depth, rz, q2);

            const bool valid = p2 > 0.001;
            const double zs = fmax(p2, 0.001);
            // f64 reciprocal: v_rcp_f64 approx + 1 Newton step (>=2^-28 rel)
#if __has_builtin(__builtin_amdgcn_rcp)
            double r = __builtin_amdgcn_rcp(zs);
#else
            double r = (double)__builtin_amdgcn_rcpf((float)zs);
            r = r * fma(-zs, r, 2.0);
#endif
            r = r * fma(-zs, r, 2.0);
            const double x = p0 * r;
            const double y = p1 * r;

            const double x0f = floor(x);
            const double y0f = floor(y);
            // sub-pixel fractions -> f32 (f64 x,y already ~1e-12-accurate)
            const float fx = (float)(x - x0f);
            const float fy = (float)(y - y0f);
            const int x0 = (int)x0f;
            const int y0 = (int)y0f;
            const int x1 = x0 + 1;
            const int y1 = y0 + 1;

            const float gx = 1.0f - fx, gy = 1.0f - fy;
            const bool okx0 = (x0 >= 0) & (x0 < W);
            const bool okx1 = (x1 >= 0) & (x1 < W);
            const bool oky0 = (y0 >= 0) & (y0 < H);
            const bool oky1 = (y1 >= 0) & (y1 < H);
            const float w00 = (valid & okx0 & oky0) ? gx * gy : 0.0f;
            const float w01 = (valid & okx1 & oky0) ? fx * gy : 0.0f;
            const float w10 = (valid & okx0 & oky1) ? gx * fy : 0.0f;
            const float w11 = (valid & okx1 & oky1) ? fx * fy : 0.0f;

            const int x0c = min(max(x0, 0), W - 1);
            const int x1c = min(max(x1, 0), W - 1);
            const int y0c = min(max(y0, 0), H - 1);
            const int y1c = min(max(y1, 0), H - 1);
            const int off00 = y0c * W + x0c;
            const int off01 = y0c * W + x1c;
            const int off10 = y1c * W + x0c;
            const int off11 = y1c * W + x1c;

            // single fused pass: bilinear + shifted-variance stats + dot
            float dot = 0.0f, st = 0.0f, s2 = 0.0f, aval = 0.0f;
            #pragma unroll
            for (int c = 0; c < C; ++c) {
                const float v00 = sb[c * HW + off00];
                const float v01 = sb[c * HW + off01];
                const float v10 = sb[c * HW + off10];
                const float v11 = sb[c * HW + off11];
                const float val = w00 * v00 + w01 * v01 + w10 * v10 + w11 * v11;
                if (c == 0) {
                    aval = val;        // shift; t_0 = 0 contributes nothing
                } else {
                    const float t = val - aval;
                    st += t;
                    s2 = fmaf(t, t, s2);
                }
                dot = fmaf(f1[c], val, dot);   // exact: Σf1 = 0
            }
            float sq2 = fmaf(-st * (1.0f / C), st, s2);
            sq2 = fmaxf(sq2, 0.0f);
            const float den = n1 * sqrtf(sq2) + 1e-6f;
            cost += dot / den;
        };

        sample(dep0, cost0);
        sample(dep1, cost1);
    }

    // out base wave-uniform -> saddr stores with voffset pix*4
    float* op = out + (size_t)(b * D + dg * ND) * HW + pix;
    op[0]  = cost0 * (1.0f / S);
    op[HW] = cost1 * (1.0f / S);
}

extern "C" void kernel_launch(void* const* d_in, const int* in_sizes, int n_in,
                              void* d_out, int out_size, void* d_ws, size_t ws_size,
                              hipStream_t stream) {
    const float* ref_feats  = (const float*)d_in[0];
    const float* src_feats  = (const float*)d_in[1];
    const float* ref_intr   = (const float*)d_in[2];
    const float* src_intr   = (const float*)d_in[3];
    const float* ref_to_src = (const float*)d_in[4];
    const float* depths     = (const float*)d_in[5];
    float* out = (float*)d_out;
    double* mats = (double*)d_ws;   // needs SB*12*8 = 576 bytes

    precompute_mats<<<1, 64, 0, stream>>>(ref_intr, src_intr, ref_to_src, mats);

    dim3 grid(HW / 256, B * G);     // 120 x 48, exact
    plane_sweep_kernel<<<grid, dim3(256), 0, stream>>>(
        ref_feats, src_feats, depths, mats, out);
}

// Round 8
// 179.988 us; speedup vs baseline: 1.0190x; 1.0190x over previous
//
#include <hip/hip_runtime.h>
#include <math.h>

// Problem constants (fixed by reference setup_inputs)
constexpr int B = 2, C = 16, H = 160, W = 192, S = 3, D = 48;
constexpr int HW = H * W;          // 30720 = 120 * 256
constexpr int SB = S * B;
constexpr int ND = 2;              // depths per thread (pairing)
constexpr int G = D / ND;          // 24 depth groups

// ------------------------------------------------------------------
// Setup kernel: per (s,b) fold projection chain into
//   A = Ks * R * inv(Kref) (3x3 f64), q = Ks * t (f64)
// so main kernel does p = depth*(A*[u,v,1]) + q.
// ws layout: (s*B+b)*12 doubles = [A row-major 0..8][q 9..11]
// ------------------------------------------------------------------
__global__ void precompute_mats(const float* __restrict__ ref_intr,
                                const float* __restrict__ src_intr,
                                const float* __restrict__ ref_to_src,
                                double* __restrict__ ws)
{
    const int i = threadIdx.x;
    if (i >= SB) return;
    const int b = i % B;

    const float* Kp = ref_intr + b * 9;
    const double a00 = Kp[0], a01 = Kp[1], a02 = Kp[2];
    const double a10 = Kp[3], a11 = Kp[4], a12 = Kp[5];
    const double a20 = Kp[6], a21 = Kp[7], a22 = Kp[8];
    const double c00 =  (a11 * a22 - a12 * a21);
    const double c01 = -(a10 * a22 - a12 * a20);
    const double c02 =  (a10 * a21 - a11 * a20);
    const double c10 = -(a01 * a22 - a02 * a21);
    const double c11 =  (a00 * a22 - a02 * a20);
    const double c12 = -(a00 * a21 - a01 * a20);
    const double c20 =  (a01 * a12 - a02 * a11);
    const double c21 = -(a00 * a12 - a02 * a10);
    const double c22 =  (a00 * a11 - a01 * a10);
    const double invdet = 1.0 / (a00 * c00 + a01 * c01 + a02 * c02);
    const double iK[9] = { c00 * invdet, c10 * invdet, c20 * invdet,
                           c01 * invdet, c11 * invdet, c21 * invdet,
                           c02 * invdet, c12 * invdet, c22 * invdet };

    const float* Tp = ref_to_src + i * 16;
    const float* Ks = src_intr + i * 9;

    double M[9];  // R * inv(K)
    #pragma unroll
    for (int r = 0; r < 3; ++r)
        #pragma unroll
        for (int c = 0; c < 3; ++c)
            M[r * 3 + c] = (double)Tp[r * 4 + 0] * iK[0 + c]
                         + (double)Tp[r * 4 + 1] * iK[3 + c]
                         + (double)Tp[r * 4 + 2] * iK[6 + c];

    double* o = ws + i * 12;
    #pragma unroll
    for (int r = 0; r < 3; ++r) {
        #pragma unroll
        for (int c = 0; c < 3; ++c)
            o[r * 3 + c] = (double)Ks[r * 3 + 0] * M[0 + c]
                         + (double)Ks[r * 3 + 1] * M[3 + c]
                         + (double)Ks[r * 3 + 2] * M[6 + c];
        o[9 + r] = (double)Ks[r * 3 + 0] * (double)Tp[3]
                 + (double)Ks[r * 3 + 1] * (double)Tp[7]
                 + (double)Ks[r * 3 + 2] * (double)Tp[11];
    }
}

// ------------------------------------------------------------------
// Main kernel. 2D grid (Round-4 win): blockIdx.y = b*G+dg keeps b/dg/s
// provably wave-uniform -> depth/mats/channel-bases scalarize (saddr
// loads, SALU address arith). NCHW stride-1 coalesced loads (Round-3
// lesson: NHWC per-thread 64B gathers amplify L1 transactions ~4x).
//
// Register policy (Rounds 2 & 5, HARD RULE): NO min-waves
// __launch_bounds__ — forced caps cause catastrophic scratch spills.
// Pressure is managed algorithmically (fused single-pass NCC,
// validated absmax 0.0039 since Round 5).
//
// Round-8: ND=2 depth-pairing, MERGED-LOOP packaging. Round 7 proved
// sharing cuts issue-cycles/output 5490 -> 4030 (-27%) but two full
// sequential sample() bodies let the scheduler interleave them ->
// VGPR 128, occupancy 20%, busy 60%. Fix: phase 1 computes BOTH
// depths' geometry into 16 named scalars (f64 dies there); phase 2 is
// ONE c-loop doing 8 loads/channel (both depths share the c*HW base
// walk) updating 8 named accumulators. Nothing left to cross-hoist;
// peak live state ~60 VGPR. Per-output numerics identical to R6/R7.
// ------------------------------------------------------------------
__global__ __launch_bounds__(256) void plane_sweep_kernel(
    const float* __restrict__ ref_feats,   // [B,C,H,W]
    const float* __restrict__ src_feats,   // [S,B,C,H,W]
    const float* __restrict__ depths,      // [D]
    const double* __restrict__ mats,       // [SB][12]
    float* __restrict__ out)               // [B,D,H,W]
{
    const int pix = blockIdx.x * 256 + threadIdx.x;   // HW = 120*256 exact
    const int by  = blockIdx.y;                       // b*G + dg (scalar)
    const int dg  = by % G;                           // scalar
    const int b   = by / G;                           // scalar

    const int w = pix % W;
    const int h = pix / W;

    // ---- ref fragment: load, zero-mean, norm (f32, well-conditioned) ----
    const float* rb = ref_feats + (size_t)b * C * HW;
    float f1[C];
    float sum1 = 0.0f;
    #pragma unroll
    for (int c = 0; c < C; ++c) { f1[c] = rb[c * HW + pix]; sum1 += f1[c]; }
    const float m1 = sum1 * (1.0f / C);
    float sq1 = 0.0f;
    #pragma unroll
    for (int c = 0; c < C; ++c) { f1[c] -= m1; sq1 = fmaf(f1[c], f1[c], sq1); }
    const float n1 = sqrtf(sq1);

    const double u = (double)w, v = (double)h;
    const double dep0 = (double)depths[dg * ND + 0];   // scalar loads
    const double dep1 = (double)depths[dg * ND + 1];

    float cost0 = 0.0f, cost1 = 0.0f;   // named accumulators (rule #20)

    #pragma unroll 1   // one source live at a time; s uniform
    for (int s = 0; s < S; ++s) {
        const double* Aq = mats + (s * B + b) * 12;   // scalar loads
        const double rx = fma(u, Aq[0], fma(v, Aq[1], Aq[2]));
        const double ry = fma(u, Aq[3], fma(v, Aq[4], Aq[5]));
        const double rz = fma(u, Aq[6], fma(v, Aq[7], Aq[8]));
        const double q0 = Aq[9], q1 = Aq[10], q2 = Aq[11];

        // ---- phase 1: geometry for both depths -> named scalars ----
        // (all f64 state is dead after this block)
        auto geom = [&](double depth,
                        float& w00, float& w01, float& w10, float& w11,
                        int& o00, int& o01, int& o10, int& o11) {
            const double p0 = fma(depth, rx, q0);
            const double p1 = fma(depth, ry, q1);
            const double p2 = fma(depth, rz, q2);

            const bool valid = p2 > 0.001;
            const double zs = fmax(p2, 0.001);
            // f64 reciprocal: v_rcp_f64 approx + 1 Newton step (>=2^-28 rel)
#if __has_builtin(__builtin_amdgcn_rcp)
            double r = __builtin_amdgcn_rcp(zs);
#else
            double r = (double)__builtin_amdgcn_rcpf((float)zs);
            r = r * fma(-zs, r, 2.0);
#endif
            r = r * fma(-zs, r, 2.0);
            const double x = p0 * r;
            const double y = p1 * r;

            const double x0f = floor(x);
            const double y0f = floor(y);
            // sub-pixel fractions -> f32 (f64 x,y already ~1e-12-accurate)
            const float fx = (float)(x - x0f);
            const float fy = (float)(y - y0f);
            const int x0 = (int)x0f;
            const int y0 = (int)y0f;
            const int x1 = x0 + 1;
            const int y1 = y0 + 1;

            const float gx = 1.0f - fx, gy = 1.0f - fy;
            const bool okx0 = (x0 >= 0) & (x0 < W);
            const bool okx1 = (x1 >= 0) & (x1 < W);
            const bool oky0 = (y0 >= 0) & (y0 < H);
            const bool oky1 = (y1 >= 0) & (y1 < H);
            w00 = (valid & okx0 & oky0) ? gx * gy : 0.0f;
            w01 = (valid & okx1 & oky0) ? fx * gy : 0.0f;
            w10 = (valid & okx0 & oky1) ? gx * fy : 0.0f;
            w11 = (valid & okx1 & oky1) ? fx * fy : 0.0f;

            const int x0c = min(max(x0, 0), W - 1);
            const int x1c = min(max(x1, 0), W - 1);
            const int y0c = min(max(y0, 0), H - 1);
            const int y1c = min(max(y1, 0), H - 1);
            o00 = y0c * W + x0c;
            o01 = y0c * W + x1c;
            o10 = y1c * W + x0c;
            o11 = y1c * W + x1c;
        };

        float wa00, wa01, wa10, wa11, wb00, wb01, wb10, wb11;
        int   oa00, oa01, oa10, oa11, ob00, ob01, ob10, ob11;
        geom(dep0, wa00, wa01, wa10, wa11, oa00, oa01, oa10, oa11);
        geom(dep1, wb00, wb01, wb10, wb11, ob00, ob01, ob10, ob11);

        // sb wave-uniform -> saddr loads; c*HW walks in SALU
        const float* sb = src_feats + (size_t)(s * B + b) * C * HW;

        // ---- phase 2: ONE merged fused pass for both depths ----
        float dot0 = 0.0f, st0 = 0.0f, s20 = 0.0f, av0 = 0.0f;
        float dot1 = 0.0f, st1 = 0.0f, s21 = 0.0f, av1 = 0.0f;
        #pragma unroll
        for (int c = 0; c < C; ++c) {
            const float* p = sb + c * HW;
            const float va00 = p[oa00];
            const float va01 = p[oa01];
            const float va10 = p[oa10];
            const float va11 = p[oa11];
            const float vb00 = p[ob00];
            const float vb01 = p[ob01];
            const float vb10 = p[ob10];
            const float vb11 = p[ob11];
            const float val0 = wa00 * va00 + wa01 * va01 + wa10 * va10 + wa11 * va11;
            const float val1 = wb00 * vb00 + wb01 * vb01 + wb10 * vb10 + wb11 * vb11;
            if (c == 0) {
                av0 = val0;            // shift; t_0 = 0 contributes nothing
                av1 = val1;
            } else {
                const float t0 = val0 - av0;
                st0 += t0;
                s20 = fmaf(t0, t0, s20);
                const float t1 = val1 - av1;
                st1 += t1;
                s21 = fmaf(t1, t1, s21);
            }
            dot0 = fmaf(f1[c], val0, dot0);   // exact: Σf1 = 0
            dot1 = fmaf(f1[c], val1, dot1);
        }
        // Σ(f2-m2)^2 = s2 - st^2/C (shifted form; clamp rounding negatives)
        float sq20 = fmaf(-st0 * (1.0f / C), st0, s20);
        sq20 = fmaxf(sq20, 0.0f);
        cost0 += dot0 / (n1 * sqrtf(sq20) + 1e-6f);
        float sq21 = fmaf(-st1 * (1.0f / C), st1, s21);
        sq21 = fmaxf(sq21, 0.0f);
        cost1 += dot1 / (n1 * sqrtf(sq21) + 1e-6f);
    }

    // out base wave-uniform -> saddr stores with voffset pix*4
    float* op = out + (size_t)(b * D + dg * ND) * HW + pix;
    op[0]  = cost0 * (1.0f / S);
    op[HW] = cost1 * (1.0f / S);
}

extern "C" void kernel_launch(void* const* d_in, const int* in_sizes, int n_in,
                              void* d_out, int out_size, void* d_ws, size_t ws_size,
                              hipStream_t stream) {
    const float* ref_feats  = (const float*)d_in[0];
    const float* src_feats  = (const float*)d_in[1];
    const float* ref_intr   = (const float*)d_in[2];
    const float* src_intr   = (const float*)d_in[3];
    const float* ref_to_src = (const float*)d_in[4];
    const float* depths     = (const float*)d_in[5];
    float* out = (float*)d_out;
    double* mats = (double*)d_ws;   // needs SB*12*8 = 576 bytes

    precompute_mats<<<1, 64, 0, stream>>>(ref_intr, src_intr, ref_to_src, mats);

    dim3 grid(HW / 256, B * G);     // 120 x 48, exact
    plane_sweep_kernel<<<grid, dim3(256), 0, stream>>>(
        ref_feats, src_feats, depths, mats, out);
}